// Round 6
// baseline (1789.803 us; speedup 1.0000x reference)
//
#include <hip/hip_runtime.h>

// HPWL, binned scatter + LDS reduce (R6).
//
// R5 post-mortem: scatter write amp (271 MB vs 80 ideal) comes from partial
// record-lines being evicted from L2 between the ~3.5 gradual fills: the
// partial-line working set was concurrent_blocks x NBK x 64B ~ 84 MB >> L2.
// R6: NB=489 (CHUNK 20480, TPB 512) and NBK=733 (buckets of 4096 nets) ->
// 23 MB partial-line set, L2-resident; pos streamed non-temporally.
// Also: record order within a bucket is irrelevant for min/max, so the
// exact counting-sort (histo + 4 scan kernels) is replaced by fixed-capacity
// buckets (CAP=16384 ~ mean+23 sigma) reserved via one global atomicAdd per
// (block,bucket) (358K atomics ~ 13 us at the measured 26.7 G/s ceiling).
// Pipeline: scatter -> reduce. p2n is read twice but the 80 KB/block chunk
// stays in L2 between passes.
//
// Encoding: order-preserving float->uint; max via atomicMax(enc), min via
// atomicMax(~enc); identity 0; tile.x==0 flags empty net. Records pack
// 26-bit x/y prefixes + 12-bit local net into 8 B (truncation is monotone;
// total error ~4e5 vs 1.9e8 threshold). net_mask arrives as int32 words.

#define BK_SHIFT 12
#define BK_NETS  4096
#define MAX_BK   1024                 // max buckets (LDS cursor array)
#define CHUNK    20480
#define TPB      512
#define CAP      16384                // records per bucket (mean 13642 + 23σ)

typedef float v4f __attribute__((ext_vector_type(4)));
typedef int   v4i __attribute__((ext_vector_type(4)));

__device__ __forceinline__ unsigned enc(float f) {
    unsigned u = __float_as_uint(f);
    return u ^ ((unsigned)((int)u >> 31) | 0x80000000u);
}
__device__ __forceinline__ float dec(unsigned u) {
    unsigned b = (u & 0x80000000u) ? (u ^ 0x80000000u) : ~u;
    return __uint_as_float(b);
}

__device__ __forceinline__ uint2 pack_rec(float x, float y, int net) {
    unsigned ex = enc(x), ey = enc(y);
    unsigned nl = (unsigned)net & (BK_NETS - 1);
    uint2 r;
    r.x = (ex & ~63u) | (nl >> 6);    // x prefix 26b | net hi 6
    r.y = (ey & ~63u) | (nl & 63u);   // y prefix 26b | net lo 6
    return r;
}

// ---------------- Phase 1: scatter with per-block slab reservation ----------------
__global__ __launch_bounds__(TPB) void scatter_kernel(
        const float* __restrict__ pos, const int* __restrict__ p2n,
        unsigned* __restrict__ gcur,    // [NBK], zeroed; ends holding counts
        uint2* __restrict__ recs,       // [NBK][CAP]
        int P, int NBK) {
    int b = blockIdx.x;
    int pstart = b * CHUNK;
    int pend = min(P, pstart + CHUNK);
    __shared__ unsigned cur[MAX_BK];
    for (int k = threadIdx.x; k < NBK; k += TPB) cur[k] = 0;
    __syncthreads();

    // pass 1: LDS histogram of this chunk
    int nv = (pend - pstart) >> 2;
    for (int g = threadIdx.x; g < nv; g += TPB) {
        int p = pstart + (g << 2);
        v4i nets = *(const v4i*)(p2n + p);
        atomicAdd(&cur[nets.x >> BK_SHIFT], 1u);
        atomicAdd(&cur[nets.y >> BK_SHIFT], 1u);
        atomicAdd(&cur[nets.z >> BK_SHIFT], 1u);
        atomicAdd(&cur[nets.w >> BK_SHIFT], 1u);
    }
    for (int p = pstart + (nv << 2) + threadIdx.x; p < pend; p += TPB)
        atomicAdd(&cur[p2n[p] >> BK_SHIFT], 1u);
    __syncthreads();

    // reserve a contiguous slab per bucket (one global atomic per non-empty bucket)
    for (int k = threadIdx.x; k < NBK; k += TPB) {
        unsigned c = cur[k];
        cur[k] = c ? atomicAdd(&gcur[k], c) : 0u;   // within-bucket base
    }
    __syncthreads();

    // pass 2: write records (p2n chunk re-read hits L2; pos non-temporal)
    for (int g = threadIdx.x; g < nv; g += TPB) {
        int p = pstart + (g << 2);
        v4i nets = *(const v4i*)(p2n + p);
        v4f xs = __builtin_nontemporal_load((const v4f*)(pos + p));
        v4f ys = __builtin_nontemporal_load((const v4f*)(pos + P + p));
        #pragma unroll
        for (int j = 0; j < 4; ++j) {
            int net = nets[j];
            int bk = net >> BK_SHIFT;
            unsigned off = atomicAdd(&cur[bk], 1u);
            if (off < CAP)
                recs[(size_t)bk * CAP + off] = pack_rec(xs[j], ys[j], net);
        }
    }
    for (int p = pstart + (nv << 2) + threadIdx.x; p < pend; p += TPB) {
        int net = p2n[p];
        int bk = net >> BK_SHIFT;
        unsigned off = atomicAdd(&cur[bk], 1u);
        if (off < CAP)
            recs[(size_t)bk * CAP + off] = pack_rec(pos[p], pos[P + p], net);
    }
}

// ---------------- Phase 2: per-bucket LDS reduce ----------------
__global__ __launch_bounds__(TPB) void reduce_kernel(
        const uint2* __restrict__ recs,
        const unsigned* __restrict__ gcur,    // per-bucket counts
        const int* __restrict__ mask,
        float* __restrict__ out, int num_nets) {
    int k = blockIdx.x;
    __shared__ unsigned tile[4 * BK_NETS];   // planes: mx, ~mn_x, my, ~mn_y (64 KB)
    for (int i = threadIdx.x; i < 4 * BK_NETS; i += TPB) tile[i] = 0;
    __syncthreads();
    unsigned cnt = min(gcur[k], (unsigned)CAP);
    const uint2* base = recs + (size_t)k * CAP;
    for (unsigned i = threadIdx.x; i < cnt; i += TPB) {
        uint2 r = base[i];
        unsigned nl = ((r.x & 63u) << 6) | (r.y & 63u);
        unsigned ex = r.x & ~63u;
        unsigned ey = r.y & ~63u;
        atomicMax(&tile[nl], ex);
        atomicMax(&tile[BK_NETS + nl], (~ex) & ~63u);
        atomicMax(&tile[2 * BK_NETS + nl], ey);
        atomicMax(&tile[3 * BK_NETS + nl], (~ey) & ~63u);
    }
    __syncthreads();
    int gbase = k << BK_SHIFT;
    int nthis = min(BK_NETS, num_nets - gbase);
    float h = 0.0f;
    for (int n = threadIdx.x; n < nthis; n += TPB) {
        unsigned a = tile[n];
        if (a != 0u && mask[gbase + n] != 0) {
            float xmax = dec(a);
            float xmin = dec(~tile[BK_NETS + n]);
            float ymax = dec(tile[2 * BK_NETS + n]);
            float ymin = dec(~tile[3 * BK_NETS + n]);
            h += (xmax - xmin) + (ymax - ymin);
        }
    }
    #pragma unroll
    for (int off = 32; off > 0; off >>= 1)
        h += __shfl_down(h, off);
    __syncthreads();                          // all tile reads done; reuse tile
    float* ws = (float*)tile;
    int wid = threadIdx.x >> 6;
    if ((threadIdx.x & 63) == 0) ws[wid] = h;
    __syncthreads();
    if (threadIdx.x == 0) {
        float t = 0.0f;
        #pragma unroll
        for (int w = 0; w < TPB / 64; ++w) t += ws[w];
        atomicAdd(out, t);
    }
}

// ---------------- Fallback: global-atomic path ----------------
__device__ __forceinline__ void upd(unsigned* __restrict__ nets,
                                    float x, float y, int net) {
    unsigned ex = enc(x), ey = enc(y);
    unsigned* base = nets + ((size_t)net << 2);
    atomicMax(base + 0, ex);
    atomicMax(base + 1, ~ex);
    atomicMax(base + 2, ey);
    atomicMax(base + 3, ~ey);
}

__global__ void fb_pin_kernel(const float* __restrict__ pos,
                              const int* __restrict__ p2n,
                              unsigned* __restrict__ nets, int num_pins) {
    int i = blockIdx.x * blockDim.x + threadIdx.x;
    if (i >= num_pins) return;
    upd(nets, pos[i], pos[i + num_pins], p2n[i]);
}

__global__ void fb_net_kernel(const uint4* __restrict__ nets,
                              const int* __restrict__ mask,
                              float* __restrict__ out, int num_nets) {
    int i = blockIdx.x * blockDim.x + threadIdx.x;
    float h = 0.0f;
    if (i < num_nets) {
        uint4 v = nets[i];
        if (v.x != 0u && mask[i] != 0)
            h = (dec(v.x) - dec(~v.y)) + (dec(v.z) - dec(~v.w));
    }
    #pragma unroll
    for (int off = 32; off > 0; off >>= 1)
        h += __shfl_down(h, off);
    __shared__ float s[4];
    int wid = threadIdx.x >> 6;
    if ((threadIdx.x & 63) == 0) s[wid] = h;
    __syncthreads();
    if (threadIdx.x == 0)
        atomicAdd(out, s[0] + s[1] + s[2] + s[3]);
}

extern "C" void kernel_launch(void* const* d_in, const int* in_sizes, int n_in,
                              void* d_out, int out_size, void* d_ws, size_t ws_size,
                              hipStream_t stream) {
    const float* pos = (const float*)d_in[0];
    const int* p2n = (const int*)d_in[1];
    const int* mask = (const int*)d_in[2];
    const int P = in_sizes[0] / 2;
    const int N = in_sizes[2];

    const int NBK = (N + BK_NETS - 1) >> BK_SHIFT;
    const int NB = (P + CHUNK - 1) / CHUNK;

    // ws: recs[NBK][CAP] (8B) | gcur[NBK]
    size_t recs_bytes = (size_t)NBK * CAP * sizeof(uint2);
    size_t need = recs_bytes + (size_t)NBK * sizeof(unsigned) + 256;

    hipMemsetAsync(d_out, 0, sizeof(float), stream);

    // Capacity check: CAP must comfortably exceed P/NBK (random pin->net map).
    bool cap_ok = (NBK > 0) && ((size_t)P / (size_t)NBK + 4096 <= CAP);

    if (NBK <= MAX_BK && ws_size >= need && cap_ok) {
        uint2* recs = (uint2*)d_ws;
        unsigned* gcur = (unsigned*)((char*)d_ws + recs_bytes);
        hipMemsetAsync(gcur, 0, (size_t)NBK * sizeof(unsigned), stream);

        scatter_kernel<<<NB, TPB, 0, stream>>>(pos, p2n, gcur, recs, P, NBK);
        reduce_kernel<<<NBK, TPB, 0, stream>>>(recs, gcur, mask, (float*)d_out, N);
    } else {
        unsigned* nets = (unsigned*)d_ws;
        hipMemsetAsync(d_ws, 0, (size_t)N * 4 * sizeof(unsigned), stream);
        fb_pin_kernel<<<(P + 255) / 256, 256, 0, stream>>>(pos, p2n, nets, P);
        fb_net_kernel<<<(N + 255) / 256, 256, 0, stream>>>((const uint4*)nets, mask,
                                                           (float*)d_out, N);
    }
}

// Round 7
// 331.227 us; speedup vs baseline: 5.4036x; 5.4036x over previous
//
#include <hip/hip_runtime.h>

// HPWL, binned scatter + LDS reduce (R7 = R6 with the capacity guard fixed).
//
// R6 post-mortem: the fast path NEVER RAN — cap_ok demanded mean+4096 <= CAP
// (17738 > 16384) and we silently took the 1.8 ms global-atomic fallback.
// Statistically CAP=16384 was already mean+23 sigma (sigma~117, expected max
// over 733 buckets ~ mean+3.6 sigma). R7: CAP=20480 (mean+58 sigma), ws need
// ~120 MB (< the >=172 MB workspace R4 used successfully).
//
// Structure: one scatter kernel (LDS histogram -> slab reservation via one
// global atomicAdd per (block,bucket) -> record write) + one reduce kernel
// (64 KB LDS tile of 4096 nets x 4 planes, LDS atomicMax, masked HPWL sum,
// one global atomicAdd per block). Partial-record-line working set:
// ~61 concurrent blocks/XCD x 733 buckets x 64 B ~ 2.9 MB < 4 MB per-XCD L2,
// so scattered 8 B record stores coalesce in L2 before one HBM writeback.
//
// Encoding: order-preserving float->uint; max via atomicMax(enc), min via
// atomicMax(~enc); identity 0; tile.x==0 flags empty net. Records pack
// 26-bit x/y prefixes + 12-bit local net into 8 B (truncation monotone,
// total error ~4e5 vs 1.9e8 threshold). net_mask arrives as int32 words.

#define BK_SHIFT 12
#define BK_NETS  4096
#define MAX_BK   1024                 // max buckets (LDS cursor array)
#define CHUNK    20480
#define TPB      512
#define CAP      20480                // records per bucket (mean 13642 + 58σ)

typedef float v4f __attribute__((ext_vector_type(4)));
typedef int   v4i __attribute__((ext_vector_type(4)));

__device__ __forceinline__ unsigned enc(float f) {
    unsigned u = __float_as_uint(f);
    return u ^ ((unsigned)((int)u >> 31) | 0x80000000u);
}
__device__ __forceinline__ float dec(unsigned u) {
    unsigned b = (u & 0x80000000u) ? (u ^ 0x80000000u) : ~u;
    return __uint_as_float(b);
}

__device__ __forceinline__ uint2 pack_rec(float x, float y, int net) {
    unsigned ex = enc(x), ey = enc(y);
    unsigned nl = (unsigned)net & (BK_NETS - 1);
    uint2 r;
    r.x = (ex & ~63u) | (nl >> 6);    // x prefix 26b | net hi 6
    r.y = (ey & ~63u) | (nl & 63u);   // y prefix 26b | net lo 6
    return r;
}

// ---------------- Phase 1: scatter with per-block slab reservation ----------------
__global__ __launch_bounds__(TPB) void scatter_kernel(
        const float* __restrict__ pos, const int* __restrict__ p2n,
        unsigned* __restrict__ gcur,    // [NBK], zeroed; ends holding counts
        uint2* __restrict__ recs,       // [NBK][CAP]
        int P, int NBK) {
    int b = blockIdx.x;
    int pstart = b * CHUNK;
    int pend = min(P, pstart + CHUNK);
    __shared__ unsigned cur[MAX_BK];
    for (int k = threadIdx.x; k < NBK; k += TPB) cur[k] = 0;
    __syncthreads();

    // pass 1: LDS histogram of this chunk
    int nv = (pend - pstart) >> 2;
    for (int g = threadIdx.x; g < nv; g += TPB) {
        int p = pstart + (g << 2);
        v4i nets = *(const v4i*)(p2n + p);
        atomicAdd(&cur[nets.x >> BK_SHIFT], 1u);
        atomicAdd(&cur[nets.y >> BK_SHIFT], 1u);
        atomicAdd(&cur[nets.z >> BK_SHIFT], 1u);
        atomicAdd(&cur[nets.w >> BK_SHIFT], 1u);
    }
    for (int p = pstart + (nv << 2) + threadIdx.x; p < pend; p += TPB)
        atomicAdd(&cur[p2n[p] >> BK_SHIFT], 1u);
    __syncthreads();

    // reserve a contiguous slab per bucket (one global atomic per non-empty bucket)
    for (int k = threadIdx.x; k < NBK; k += TPB) {
        unsigned c = cur[k];
        cur[k] = c ? atomicAdd(&gcur[k], c) : 0u;   // within-bucket base
    }
    __syncthreads();

    // pass 2: write records (p2n chunk re-read hits L2; pos non-temporal)
    for (int g = threadIdx.x; g < nv; g += TPB) {
        int p = pstart + (g << 2);
        v4i nets = *(const v4i*)(p2n + p);
        v4f xs = __builtin_nontemporal_load((const v4f*)(pos + p));
        v4f ys = __builtin_nontemporal_load((const v4f*)(pos + P + p));
        #pragma unroll
        for (int j = 0; j < 4; ++j) {
            int net = nets[j];
            int bk = net >> BK_SHIFT;
            unsigned off = atomicAdd(&cur[bk], 1u);
            if (off < CAP)
                recs[(size_t)bk * CAP + off] = pack_rec(xs[j], ys[j], net);
        }
    }
    for (int p = pstart + (nv << 2) + threadIdx.x; p < pend; p += TPB) {
        int net = p2n[p];
        int bk = net >> BK_SHIFT;
        unsigned off = atomicAdd(&cur[bk], 1u);
        if (off < CAP)
            recs[(size_t)bk * CAP + off] = pack_rec(pos[p], pos[P + p], net);
    }
}

// ---------------- Phase 2: per-bucket LDS reduce ----------------
__global__ __launch_bounds__(TPB) void reduce_kernel(
        const uint2* __restrict__ recs,
        const unsigned* __restrict__ gcur,    // per-bucket counts
        const int* __restrict__ mask,
        float* __restrict__ out, int num_nets) {
    int k = blockIdx.x;
    __shared__ unsigned tile[4 * BK_NETS];   // planes: mx, ~mn_x, my, ~mn_y (64 KB)
    for (int i = threadIdx.x; i < 4 * BK_NETS; i += TPB) tile[i] = 0;
    __syncthreads();
    unsigned cnt = min(gcur[k], (unsigned)CAP);
    const uint2* base = recs + (size_t)k * CAP;
    for (unsigned i = threadIdx.x; i < cnt; i += TPB) {
        uint2 r = base[i];
        unsigned nl = ((r.x & 63u) << 6) | (r.y & 63u);
        unsigned ex = r.x & ~63u;
        unsigned ey = r.y & ~63u;
        atomicMax(&tile[nl], ex);
        atomicMax(&tile[BK_NETS + nl], (~ex) & ~63u);
        atomicMax(&tile[2 * BK_NETS + nl], ey);
        atomicMax(&tile[3 * BK_NETS + nl], (~ey) & ~63u);
    }
    __syncthreads();
    int gbase = k << BK_SHIFT;
    int nthis = min(BK_NETS, num_nets - gbase);
    float h = 0.0f;
    for (int n = threadIdx.x; n < nthis; n += TPB) {
        unsigned a = tile[n];
        if (a != 0u && mask[gbase + n] != 0) {
            float xmax = dec(a);
            float xmin = dec(~tile[BK_NETS + n]);
            float ymax = dec(tile[2 * BK_NETS + n]);
            float ymin = dec(~tile[3 * BK_NETS + n]);
            h += (xmax - xmin) + (ymax - ymin);
        }
    }
    #pragma unroll
    for (int off = 32; off > 0; off >>= 1)
        h += __shfl_down(h, off);
    __syncthreads();                          // all tile reads done; reuse tile
    float* ws = (float*)tile;
    int wid = threadIdx.x >> 6;
    if ((threadIdx.x & 63) == 0) ws[wid] = h;
    __syncthreads();
    if (threadIdx.x == 0) {
        float t = 0.0f;
        #pragma unroll
        for (int w = 0; w < TPB / 64; ++w) t += ws[w];
        atomicAdd(out, t);
    }
}

// ---------------- Fallback: global-atomic path ----------------
__device__ __forceinline__ void upd(unsigned* __restrict__ nets,
                                    float x, float y, int net) {
    unsigned ex = enc(x), ey = enc(y);
    unsigned* base = nets + ((size_t)net << 2);
    atomicMax(base + 0, ex);
    atomicMax(base + 1, ~ex);
    atomicMax(base + 2, ey);
    atomicMax(base + 3, ~ey);
}

__global__ void fb_pin_kernel(const float* __restrict__ pos,
                              const int* __restrict__ p2n,
                              unsigned* __restrict__ nets, int num_pins) {
    int i = blockIdx.x * blockDim.x + threadIdx.x;
    if (i >= num_pins) return;
    upd(nets, pos[i], pos[i + num_pins], p2n[i]);
}

__global__ void fb_net_kernel(const uint4* __restrict__ nets,
                              const int* __restrict__ mask,
                              float* __restrict__ out, int num_nets) {
    int i = blockIdx.x * blockDim.x + threadIdx.x;
    float h = 0.0f;
    if (i < num_nets) {
        uint4 v = nets[i];
        if (v.x != 0u && mask[i] != 0)
            h = (dec(v.x) - dec(~v.y)) + (dec(v.z) - dec(~v.w));
    }
    #pragma unroll
    for (int off = 32; off > 0; off >>= 1)
        h += __shfl_down(h, off);
    __shared__ float s[4];
    int wid = threadIdx.x >> 6;
    if ((threadIdx.x & 63) == 0) s[wid] = h;
    __syncthreads();
    if (threadIdx.x == 0)
        atomicAdd(out, s[0] + s[1] + s[2] + s[3]);
}

extern "C" void kernel_launch(void* const* d_in, const int* in_sizes, int n_in,
                              void* d_out, int out_size, void* d_ws, size_t ws_size,
                              hipStream_t stream) {
    const float* pos = (const float*)d_in[0];
    const int* p2n = (const int*)d_in[1];
    const int* mask = (const int*)d_in[2];
    const int P = in_sizes[0] / 2;
    const int N = in_sizes[2];

    const int NBK = (N + BK_NETS - 1) >> BK_SHIFT;
    const int NB = (P + CHUNK - 1) / CHUNK;

    // ws: recs[NBK][CAP] (8B) | gcur[NBK]
    size_t recs_bytes = (size_t)NBK * CAP * sizeof(uint2);
    size_t need = recs_bytes + (size_t)NBK * sizeof(unsigned) + 256;

    hipMemsetAsync(d_out, 0, sizeof(float), stream);

    // Guard: mean load + 8*sqrt(mean) + 512 must fit (random map: sigma ~ sqrt(mean),
    // expected max over NBK buckets ~ mean + 4 sigma; 8 sigma + 512 is generous).
    size_t mean_load = (NBK > 0) ? (size_t)P / (size_t)NBK : 0;
    size_t slack = 8 * (size_t)(__builtin_sqrt((double)(mean_load + 1))) + 512;
    bool cap_ok = (NBK > 0) && (mean_load + slack <= CAP);

    if (NBK <= MAX_BK && ws_size >= need && cap_ok) {
        uint2* recs = (uint2*)d_ws;
        unsigned* gcur = (unsigned*)((char*)d_ws + recs_bytes);
        hipMemsetAsync(gcur, 0, (size_t)NBK * sizeof(unsigned), stream);

        scatter_kernel<<<NB, TPB, 0, stream>>>(pos, p2n, gcur, recs, P, NBK);
        reduce_kernel<<<NBK, TPB, 0, stream>>>(recs, gcur, mask, (float*)d_out, N);
    } else {
        unsigned* nets = (unsigned*)d_ws;
        hipMemsetAsync(d_ws, 0, (size_t)N * 4 * sizeof(unsigned), stream);
        fb_pin_kernel<<<(P + 255) / 256, 256, 0, stream>>>(pos, p2n, nets, P);
        fb_net_kernel<<<(N + 255) / 256, 256, 0, stream>>>((const uint4*)nets, mask,
                                                           (float*)d_out, N);
    }
}

// Round 8
// 299.088 us; speedup vs baseline: 5.9842x; 1.1075x over previous
//
#include <hip/hip_runtime.h>

// HPWL via block-local counting sort + per-bucket LDS reduce (R8).
//
// R7 post-mortem: scatter was L2-request-bound (10M random 8B stores, 64
// line-touches per wave-store; 2.1 TB/s, VALUBusy 3.7% => not BW-bound), and
// WRITE_SIZE stayed 271 MB (partial-line RFO/eviction thrash). R8 removes
// random global stores entirely: each block counting-sorts its 24576-pin
// chunk in LDS (4 staged 6144-rec passes) and writes records GROUPED by
// bucket with wave-contiguous coalesced stores into its own deterministic
// region recs[b*CHUNK..]. A {start,count} directory per (block,bucket) lets
// the reducer gather segments coalesced. Zero global atomics except one
// atomicAdd(out) per reduce block.
//
// Encoding: order-preserving float->uint (enc); max via LDS atomicMax(enc),
// min via atomicMax(~enc); identity 0; plane.x==0 flags empty net. Records
// pack 26-bit x/y prefixes + 12-bit local net into 8 B (truncation is
// monotone; max/min biases cancel in (max-min); total error << 1.9e8
// threshold). net_mask arrives as int32 words.

#define BK_SHIFT 12
#define BK_NETS  4096
#define NBK_MAX  736                  // bucket-array LDS size (N <= ~3.01M)
#define SUB      6144                 // pins staged per sub-pass (48 KB)
#define NSUB     4
#define CHUNK    (SUB * NSUB)         // 24576 pins per block
#define TPB      1024
#define RTPB     512

typedef float v4f __attribute__((ext_vector_type(4)));
typedef int   v4i __attribute__((ext_vector_type(4)));

__device__ __forceinline__ unsigned enc(float f) {
    unsigned u = __float_as_uint(f);
    return u ^ ((unsigned)((int)u >> 31) | 0x80000000u);
}
__device__ __forceinline__ float dec(unsigned u) {
    unsigned b = (u & 0x80000000u) ? (u ^ 0x80000000u) : ~u;
    return __uint_as_float(b);
}
__device__ __forceinline__ uint2 pack_rec(float x, float y, int net) {
    unsigned ex = enc(x), ey = enc(y);
    unsigned nl = (unsigned)net & (BK_NETS - 1);
    uint2 r;
    r.x = (ex & ~63u) | (nl >> 6);    // x prefix 26b | net hi 6
    r.y = (ey & ~63u) | (nl & 63u);   // y prefix 26b | net lo 6
    return r;
}

// Exclusive scan of arr[0..n) (n <= 1024) across 1024 threads, Hillis-Steele
// ping-pong in bufA/bufB. All threads must call.
__device__ __forceinline__ void block_scan_excl(unsigned* arr, int n,
                                                unsigned* bufA, unsigned* bufB) {
    int t = threadIdx.x;
    unsigned v = (t < n) ? arr[t] : 0u;
    bufA[t] = v;
    __syncthreads();
    unsigned* s = bufA;
    unsigned* d = bufB;
    #pragma unroll
    for (int off = 1; off < 1024; off <<= 1) {
        unsigned x = s[t];
        if (t >= off) x += s[t - off];
        d[t] = x;
        __syncthreads();
        unsigned* tmp = s; s = d; d = tmp;
    }
    if (t < n) arr[t] = s[t] - v;     // inclusive -> exclusive
    __syncthreads();
}

// ---------------- Phase 1: block-local counting sort ----------------
__global__ __launch_bounds__(TPB) void scatter_kernel(
        const float* __restrict__ pos, const int* __restrict__ p2n,
        uint2* __restrict__ recs,       // [P], block b owns [b*CHUNK, +pcount)
        unsigned* __restrict__ dir,     // [NB][NBK]: start | (count<<16)
        int P, int NBK) {
    __shared__ uint2    stage[SUB];       // 48 KB
    __shared__ unsigned hist[NBK_MAX];    // full-chunk hist -> fstart after scan
    __shared__ unsigned fc[NBK_MAX];      // per-bucket fill cursor
    __shared__ unsigned sstart[NBK_MAX];  // sub-pass group starts
    __shared__ unsigned scur[NBK_MAX];    // sub-pass scatter cursors
    __shared__ unsigned scanA[1024], scanB[1024];

    const int b = blockIdx.x;
    const int pstart = b * CHUNK;
    const int pcount = min(P - pstart, CHUNK);   // multiple of 4 (P%4==0)

    for (int k = threadIdx.x; k < NBK; k += TPB) { hist[k] = 0; fc[k] = 0; }
    __syncthreads();

    // full-chunk histogram
    int nv = pcount >> 2;
    for (int g = threadIdx.x; g < nv; g += TPB) {
        v4i n4 = *(const v4i*)(p2n + pstart + (g << 2));
        atomicAdd(&hist[n4.x >> BK_SHIFT], 1u);
        atomicAdd(&hist[n4.y >> BK_SHIFT], 1u);
        atomicAdd(&hist[n4.z >> BK_SHIFT], 1u);
        atomicAdd(&hist[n4.w >> BK_SHIFT], 1u);
    }
    __syncthreads();
    block_scan_excl(hist, NBK, scanA, scanB);    // hist = fstart

    for (int s = 0; s < NSUB; ++s) {
        int sbase = pstart + s * SUB;
        int scount = min(pcount - s * SUB, SUB);
        if (scount <= 0) break;
        int snv = scount >> 2;                   // scount multiple of 4

        for (int k = threadIdx.x; k < NBK; k += TPB) sstart[k] = 0;
        __syncthreads();
        for (int g = threadIdx.x; g < snv; g += TPB) {
            v4i n4 = *(const v4i*)(p2n + sbase + (g << 2));
            atomicAdd(&sstart[n4.x >> BK_SHIFT], 1u);
            atomicAdd(&sstart[n4.y >> BK_SHIFT], 1u);
            atomicAdd(&sstart[n4.z >> BK_SHIFT], 1u);
            atomicAdd(&sstart[n4.w >> BK_SHIFT], 1u);
        }
        __syncthreads();
        block_scan_excl(sstart, NBK, scanA, scanB);
        for (int k = threadIdx.x; k < NBK; k += TPB) scur[k] = sstart[k];
        __syncthreads();

        // scatter records into LDS groups
        for (int g = threadIdx.x; g < snv; g += TPB) {
            int p = sbase + (g << 2);
            v4i n4 = *(const v4i*)(p2n + p);
            v4f xs = __builtin_nontemporal_load((const v4f*)(pos + p));
            v4f ys = __builtin_nontemporal_load((const v4f*)(pos + P + p));
            unsigned s0 = atomicAdd(&scur[n4.x >> BK_SHIFT], 1u);
            stage[s0] = pack_rec(xs.x, ys.x, n4.x);
            unsigned s1 = atomicAdd(&scur[n4.y >> BK_SHIFT], 1u);
            stage[s1] = pack_rec(xs.y, ys.y, n4.y);
            unsigned s2 = atomicAdd(&scur[n4.z >> BK_SHIFT], 1u);
            stage[s2] = pack_rec(xs.z, ys.z, n4.z);
            unsigned s3 = atomicAdd(&scur[n4.w >> BK_SHIFT], 1u);
            stage[s3] = pack_rec(xs.w, ys.w, n4.w);
        }
        __syncthreads();

        // writeout: one wave per bucket, contiguous coalesced stores
        int wid = threadIdx.x >> 6, lane = threadIdx.x & 63, nw = TPB >> 6;
        for (int bk = wid; bk < NBK; bk += nw) {
            unsigned st = sstart[bk];
            unsigned cnt = scur[bk] - st;
            size_t dst = (size_t)pstart + hist[bk] + fc[bk];
            for (unsigned j = lane; j < cnt; j += 64)
                recs[dst + j] = stage[st + j];
            if (lane == 0) fc[bk] += cnt;        // bucket owned by this wave
        }
        __syncthreads();
    }

    // directory: start | count<<16 (both < 65536 since CHUNK = 24576)
    for (int k = threadIdx.x; k < NBK; k += TPB)
        dir[(size_t)b * NBK + k] = hist[k] | (fc[k] << 16);
}

// ---------------- Phase 2: per-bucket LDS reduce ----------------
__global__ __launch_bounds__(RTPB) void reduce_kernel(
        const uint2* __restrict__ recs,
        const unsigned* __restrict__ dir,
        const int* __restrict__ mask,
        float* __restrict__ out, int num_nets, int NB, int NBK) {
    int k = blockIdx.x;
    __shared__ unsigned tile[4 * BK_NETS];   // planes: mx, ~mn_x, my, ~mn_y (64 KB)
    for (int i = threadIdx.x; i < 4 * BK_NETS; i += RTPB) tile[i] = 0;
    __syncthreads();

    int wid = threadIdx.x >> 6, lane = threadIdx.x & 63, nw = RTPB >> 6;
    for (int b = wid; b < NB; b += nw) {
        unsigned d = dir[(size_t)b * NBK + k];
        unsigned st = d & 0xFFFFu, cnt = d >> 16;
        const uint2* seg = recs + (size_t)b * CHUNK + st;
        for (unsigned j = lane; j < cnt; j += 64) {
            uint2 r = seg[j];
            unsigned nl = ((r.x & 63u) << 6) | (r.y & 63u);
            unsigned ex = r.x & ~63u;
            unsigned ey = r.y & ~63u;
            atomicMax(&tile[nl], ex);
            atomicMax(&tile[BK_NETS + nl], (~ex) & ~63u);
            atomicMax(&tile[2 * BK_NETS + nl], ey);
            atomicMax(&tile[3 * BK_NETS + nl], (~ey) & ~63u);
        }
    }
    __syncthreads();

    int gbase = k << BK_SHIFT;
    int nthis = min(BK_NETS, num_nets - gbase);
    float h = 0.0f;
    for (int n = threadIdx.x; n < nthis; n += RTPB) {
        unsigned a = tile[n];
        if (a != 0u && mask[gbase + n] != 0) {
            float xmax = dec(a);
            float xmin = dec(~tile[BK_NETS + n]);
            float ymax = dec(tile[2 * BK_NETS + n]);
            float ymin = dec(~tile[3 * BK_NETS + n]);
            h += (xmax - xmin) + (ymax - ymin);
        }
    }
    #pragma unroll
    for (int off = 32; off > 0; off >>= 1)
        h += __shfl_down(h, off);
    __syncthreads();                          // tile reads done; reuse as scratch
    float* ws = (float*)tile;
    int wid2 = threadIdx.x >> 6;
    if ((threadIdx.x & 63) == 0) ws[wid2] = h;
    __syncthreads();
    if (threadIdx.x == 0) {
        float t = 0.0f;
        #pragma unroll
        for (int w = 0; w < RTPB / 64; ++w) t += ws[w];
        atomicAdd(out, t);
    }
}

// ---------------- Fallback: global-atomic path ----------------
__device__ __forceinline__ void upd(unsigned* __restrict__ nets,
                                    float x, float y, int net) {
    unsigned ex = enc(x), ey = enc(y);
    unsigned* base = nets + ((size_t)net << 2);
    atomicMax(base + 0, ex);
    atomicMax(base + 1, ~ex);
    atomicMax(base + 2, ey);
    atomicMax(base + 3, ~ey);
}

__global__ void fb_pin_kernel(const float* __restrict__ pos,
                              const int* __restrict__ p2n,
                              unsigned* __restrict__ nets, int num_pins) {
    int i = blockIdx.x * blockDim.x + threadIdx.x;
    if (i >= num_pins) return;
    upd(nets, pos[i], pos[i + num_pins], p2n[i]);
}

__global__ void fb_net_kernel(const uint4* __restrict__ nets,
                              const int* __restrict__ mask,
                              float* __restrict__ out, int num_nets) {
    int i = blockIdx.x * blockDim.x + threadIdx.x;
    float h = 0.0f;
    if (i < num_nets) {
        uint4 v = nets[i];
        if (v.x != 0u && mask[i] != 0)
            h = (dec(v.x) - dec(~v.y)) + (dec(v.z) - dec(~v.w));
    }
    #pragma unroll
    for (int off = 32; off > 0; off >>= 1)
        h += __shfl_down(h, off);
    __shared__ float s[4];
    int wid = threadIdx.x >> 6;
    if ((threadIdx.x & 63) == 0) s[wid] = h;
    __syncthreads();
    if (threadIdx.x == 0)
        atomicAdd(out, s[0] + s[1] + s[2] + s[3]);
}

extern "C" void kernel_launch(void* const* d_in, const int* in_sizes, int n_in,
                              void* d_out, int out_size, void* d_ws, size_t ws_size,
                              hipStream_t stream) {
    const float* pos = (const float*)d_in[0];
    const int* p2n = (const int*)d_in[1];
    const int* mask = (const int*)d_in[2];
    const int P = in_sizes[0] / 2;
    const int N = in_sizes[2];

    const int NBK = (N + BK_NETS - 1) >> BK_SHIFT;
    const int NB = (P + CHUNK - 1) / CHUNK;

    // ws: recs[P] (8 B) | dir[NB*NBK] (4 B)
    size_t recs_bytes = (size_t)P * sizeof(uint2);
    size_t dir_bytes = (size_t)NB * NBK * sizeof(unsigned);
    size_t need = recs_bytes + dir_bytes + 256;

    hipMemsetAsync(d_out, 0, sizeof(float), stream);

    if (NBK > 0 && NBK <= NBK_MAX && (P & 3) == 0 && ws_size >= need) {
        uint2* recs = (uint2*)d_ws;
        unsigned* dir = (unsigned*)((char*)d_ws + recs_bytes);

        scatter_kernel<<<NB, TPB, 0, stream>>>(pos, p2n, recs, dir, P, NBK);
        reduce_kernel<<<NBK, RTPB, 0, stream>>>(recs, dir, mask,
                                                (float*)d_out, N, NB, NBK);
    } else {
        unsigned* nets = (unsigned*)d_ws;
        hipMemsetAsync(d_ws, 0, (size_t)N * 4 * sizeof(unsigned), stream);
        fb_pin_kernel<<<(P + 255) / 256, 256, 0, stream>>>(pos, p2n, nets, P);
        fb_net_kernel<<<(N + 255) / 256, 256, 0, stream>>>((const uint4*)nets, mask,
                                                           (float*)d_out, N);
    }
}

// Round 9
// 264.575 us; speedup vs baseline: 6.7648x; 1.1304x over previous
//
#include <hip/hip_runtime.h>

// HPWL: block-local LDS counting sort -> per-bucket global slabs -> slab-
// streaming LDS reduce (R9).
//
// R8 post-mortem: coalesced grouped writeout fixed scatter (WRITE_SIZE 271
// ->108 MB, dur 171->106 us) but the reduce's directory gather (avg 33.5-rec
// segments, 64-lane waves half idle) ate the win. R9 keeps R8's scatter
// write path but lands records in per-bucket slabs (base reserved with one
// global atomicAdd per (block,bucket), ~300K atomics ~ 11 us) so the reduce
// streams each bucket fully coalesced (uint4, 2 recs/lane). The full-chunk
// block scan is gone (reservation replaces it).
//
// Encoding: order-preserving float->uint (enc); max via LDS atomicMax(enc),
// min via atomicMax(~enc); identity 0; plane.x==0 flags empty net. Records
// pack 26-bit x/y prefixes + 12-bit local net into 8 B (truncation monotone;
// error ~4e5 << 1.9e8 threshold). net_mask arrives as int32 words.

#define BK_SHIFT 12
#define BK_NETS  4096
#define NBK_MAX  736                  // bucket-array LDS size (N <= ~3.01M)
#define SUB      6144                 // pins staged per sub-pass (48 KB)
#define NSUB     4
#define CHUNK    (SUB * NSUB)         // 24576 pins per block
#define TPB      1024
#define RTPB     512
#define CAP      20480                // slab records per bucket (mean 13642 + 58σ)

typedef float v4f __attribute__((ext_vector_type(4)));
typedef int   v4i __attribute__((ext_vector_type(4)));

__device__ __forceinline__ unsigned enc(float f) {
    unsigned u = __float_as_uint(f);
    return u ^ ((unsigned)((int)u >> 31) | 0x80000000u);
}
__device__ __forceinline__ float dec(unsigned u) {
    unsigned b = (u & 0x80000000u) ? (u ^ 0x80000000u) : ~u;
    return __uint_as_float(b);
}
__device__ __forceinline__ uint2 pack_rec(float x, float y, int net) {
    unsigned ex = enc(x), ey = enc(y);
    unsigned nl = (unsigned)net & (BK_NETS - 1);
    uint2 r;
    r.x = (ex & ~63u) | (nl >> 6);    // x prefix 26b | net hi 6
    r.y = (ey & ~63u) | (nl & 63u);   // y prefix 26b | net lo 6
    return r;
}

// Exclusive scan of arr[0..n) (n <= 1024) across TPB threads, Hillis-Steele
// ping-pong in bufA/bufB. All threads must call.
__device__ __forceinline__ void block_scan_excl(unsigned* arr, int n,
                                                unsigned* bufA, unsigned* bufB) {
    int t = threadIdx.x;
    unsigned v = (t < n) ? arr[t] : 0u;
    bufA[t] = v;
    __syncthreads();
    unsigned* s = bufA;
    unsigned* d = bufB;
    #pragma unroll
    for (int off = 1; off < 1024; off <<= 1) {
        unsigned x = s[t];
        if (t >= off) x += s[t - off];
        d[t] = x;
        __syncthreads();
        unsigned* tmp = s; s = d; d = tmp;
    }
    if (t < n) arr[t] = s[t] - v;     // inclusive -> exclusive
    __syncthreads();
}

// ---------------- Phase 1: sort chunk in LDS, append to bucket slabs ----------------
__global__ __launch_bounds__(TPB) void scatter_kernel(
        const float* __restrict__ pos, const int* __restrict__ p2n,
        unsigned* __restrict__ gcur,    // [NBK] zeroed; ends holding counts
        uint2* __restrict__ recs,       // [NBK][CAP]
        int P, int NBK) {
    __shared__ uint2    stage[SUB];       // 48 KB
    __shared__ unsigned hist[NBK_MAX];    // full-chunk counts
    __shared__ unsigned slab[NBK_MAX];    // within-bucket slab base
    __shared__ unsigned fc[NBK_MAX];      // fill cursor within our slab
    __shared__ unsigned sstart[NBK_MAX];  // sub-pass group starts
    __shared__ unsigned scur[NBK_MAX];    // sub-pass scatter cursors
    __shared__ unsigned scanA[1024], scanB[1024];

    const int b = blockIdx.x;
    const int pstart = b * CHUNK;
    const int pcount = min(P - pstart, CHUNK);   // multiple of 4 (P%4==0)

    for (int k = threadIdx.x; k < NBK; k += TPB) { hist[k] = 0; fc[k] = 0; }
    __syncthreads();

    // full-chunk histogram
    int nv = pcount >> 2;
    for (int g = threadIdx.x; g < nv; g += TPB) {
        v4i n4 = *(const v4i*)(p2n + pstart + (g << 2));
        atomicAdd(&hist[n4.x >> BK_SHIFT], 1u);
        atomicAdd(&hist[n4.y >> BK_SHIFT], 1u);
        atomicAdd(&hist[n4.z >> BK_SHIFT], 1u);
        atomicAdd(&hist[n4.w >> BK_SHIFT], 1u);
    }
    __syncthreads();

    // reserve slab space (one global atomic per non-empty bucket)
    for (int k = threadIdx.x; k < NBK; k += TPB) {
        unsigned c = hist[k];
        slab[k] = c ? atomicAdd(&gcur[k], c) : 0u;
    }
    __syncthreads();

    for (int s = 0; s < NSUB; ++s) {
        int sbase = pstart + s * SUB;
        int scount = min(pcount - s * SUB, SUB);
        if (scount <= 0) break;
        int snv = scount >> 2;

        for (int k = threadIdx.x; k < NBK; k += TPB) sstart[k] = 0;
        __syncthreads();
        for (int g = threadIdx.x; g < snv; g += TPB) {
            v4i n4 = *(const v4i*)(p2n + sbase + (g << 2));
            atomicAdd(&sstart[n4.x >> BK_SHIFT], 1u);
            atomicAdd(&sstart[n4.y >> BK_SHIFT], 1u);
            atomicAdd(&sstart[n4.z >> BK_SHIFT], 1u);
            atomicAdd(&sstart[n4.w >> BK_SHIFT], 1u);
        }
        __syncthreads();
        block_scan_excl(sstart, NBK, scanA, scanB);
        for (int k = threadIdx.x; k < NBK; k += TPB) scur[k] = sstart[k];
        __syncthreads();

        // scatter records into LDS groups
        for (int g = threadIdx.x; g < snv; g += TPB) {
            int p = sbase + (g << 2);
            v4i n4 = *(const v4i*)(p2n + p);
            v4f xs = __builtin_nontemporal_load((const v4f*)(pos + p));
            v4f ys = __builtin_nontemporal_load((const v4f*)(pos + P + p));
            unsigned s0 = atomicAdd(&scur[n4.x >> BK_SHIFT], 1u);
            stage[s0] = pack_rec(xs.x, ys.x, n4.x);
            unsigned s1 = atomicAdd(&scur[n4.y >> BK_SHIFT], 1u);
            stage[s1] = pack_rec(xs.y, ys.y, n4.y);
            unsigned s2 = atomicAdd(&scur[n4.z >> BK_SHIFT], 1u);
            stage[s2] = pack_rec(xs.z, ys.z, n4.z);
            unsigned s3 = atomicAdd(&scur[n4.w >> BK_SHIFT], 1u);
            stage[s3] = pack_rec(xs.w, ys.w, n4.w);
        }
        __syncthreads();

        // writeout: one wave per bucket, contiguous coalesced stores to slab
        int wid = threadIdx.x >> 6, lane = threadIdx.x & 63, nw = TPB >> 6;
        for (int bk = wid; bk < NBK; bk += nw) {
            unsigned st = sstart[bk];
            unsigned cnt = scur[bk] - st;
            unsigned base = slab[bk] + fc[bk];
            size_t dst = (size_t)bk * CAP + base;
            for (unsigned j = lane; j < cnt; j += 64)
                if (base + j < CAP)
                    recs[dst + j] = stage[st + j];
            if (lane == 0) fc[bk] += cnt;        // bucket owned by this wave
        }
        __syncthreads();
    }
}

// ---------------- Phase 2: per-bucket slab-streaming LDS reduce ----------------
__global__ __launch_bounds__(RTPB) void reduce_kernel(
        const uint2* __restrict__ recs,
        const unsigned* __restrict__ gcur,
        const int* __restrict__ mask,
        float* __restrict__ out, int num_nets) {
    int k = blockIdx.x;
    __shared__ unsigned tile[4 * BK_NETS];   // planes: mx, ~mn_x, my, ~mn_y (64 KB)
    for (int i = threadIdx.x; i < 4 * BK_NETS; i += RTPB) tile[i] = 0;
    __syncthreads();

    unsigned cnt = min(gcur[k], (unsigned)CAP);
    const uint2* base = recs + (size_t)k * CAP;
    const uint4* b4 = (const uint4*)base;     // CAP even -> 16B aligned
    unsigned nv = cnt >> 1;
    for (unsigned i = threadIdx.x; i < nv; i += RTPB) {
        uint4 q = b4[i];
        unsigned nl0 = ((q.x & 63u) << 6) | (q.y & 63u);
        unsigned ex0 = q.x & ~63u, ey0 = q.y & ~63u;
        atomicMax(&tile[nl0], ex0);
        atomicMax(&tile[BK_NETS + nl0], (~ex0) & ~63u);
        atomicMax(&tile[2 * BK_NETS + nl0], ey0);
        atomicMax(&tile[3 * BK_NETS + nl0], (~ey0) & ~63u);
        unsigned nl1 = ((q.z & 63u) << 6) | (q.w & 63u);
        unsigned ex1 = q.z & ~63u, ey1 = q.w & ~63u;
        atomicMax(&tile[nl1], ex1);
        atomicMax(&tile[BK_NETS + nl1], (~ex1) & ~63u);
        atomicMax(&tile[2 * BK_NETS + nl1], ey1);
        atomicMax(&tile[3 * BK_NETS + nl1], (~ey1) & ~63u);
    }
    if ((cnt & 1u) && threadIdx.x == 0) {
        uint2 r = base[cnt - 1];
        unsigned nl = ((r.x & 63u) << 6) | (r.y & 63u);
        unsigned ex = r.x & ~63u, ey = r.y & ~63u;
        atomicMax(&tile[nl], ex);
        atomicMax(&tile[BK_NETS + nl], (~ex) & ~63u);
        atomicMax(&tile[2 * BK_NETS + nl], ey);
        atomicMax(&tile[3 * BK_NETS + nl], (~ey) & ~63u);
    }
    __syncthreads();

    int gbase = k << BK_SHIFT;
    int nthis = min(BK_NETS, num_nets - gbase);
    float h = 0.0f;
    for (int n = threadIdx.x; n < nthis; n += RTPB) {
        unsigned a = tile[n];
        if (a != 0u && mask[gbase + n] != 0) {
            float xmax = dec(a);
            float xmin = dec(~tile[BK_NETS + n]);
            float ymax = dec(tile[2 * BK_NETS + n]);
            float ymin = dec(~tile[3 * BK_NETS + n]);
            h += (xmax - xmin) + (ymax - ymin);
        }
    }
    #pragma unroll
    for (int off = 32; off > 0; off >>= 1)
        h += __shfl_down(h, off);
    __syncthreads();                          // tile reads done; reuse as scratch
    float* ws = (float*)tile;
    int wid2 = threadIdx.x >> 6;
    if ((threadIdx.x & 63) == 0) ws[wid2] = h;
    __syncthreads();
    if (threadIdx.x == 0) {
        float t = 0.0f;
        #pragma unroll
        for (int w = 0; w < RTPB / 64; ++w) t += ws[w];
        atomicAdd(out, t);
    }
}

// ---------------- Fallback: global-atomic path ----------------
__device__ __forceinline__ void upd(unsigned* __restrict__ nets,
                                    float x, float y, int net) {
    unsigned ex = enc(x), ey = enc(y);
    unsigned* base = nets + ((size_t)net << 2);
    atomicMax(base + 0, ex);
    atomicMax(base + 1, ~ex);
    atomicMax(base + 2, ey);
    atomicMax(base + 3, ~ey);
}

__global__ void fb_pin_kernel(const float* __restrict__ pos,
                              const int* __restrict__ p2n,
                              unsigned* __restrict__ nets, int num_pins) {
    int i = blockIdx.x * blockDim.x + threadIdx.x;
    if (i >= num_pins) return;
    upd(nets, pos[i], pos[i + num_pins], p2n[i]);
}

__global__ void fb_net_kernel(const uint4* __restrict__ nets,
                              const int* __restrict__ mask,
                              float* __restrict__ out, int num_nets) {
    int i = blockIdx.x * blockDim.x + threadIdx.x;
    float h = 0.0f;
    if (i < num_nets) {
        uint4 v = nets[i];
        if (v.x != 0u && mask[i] != 0)
            h = (dec(v.x) - dec(~v.y)) + (dec(v.z) - dec(~v.w));
    }
    #pragma unroll
    for (int off = 32; off > 0; off >>= 1)
        h += __shfl_down(h, off);
    __shared__ float s[4];
    int wid = threadIdx.x >> 6;
    if ((threadIdx.x & 63) == 0) s[wid] = h;
    __syncthreads();
    if (threadIdx.x == 0)
        atomicAdd(out, s[0] + s[1] + s[2] + s[3]);
}

extern "C" void kernel_launch(void* const* d_in, const int* in_sizes, int n_in,
                              void* d_out, int out_size, void* d_ws, size_t ws_size,
                              hipStream_t stream) {
    const float* pos = (const float*)d_in[0];
    const int* p2n = (const int*)d_in[1];
    const int* mask = (const int*)d_in[2];
    const int P = in_sizes[0] / 2;
    const int N = in_sizes[2];

    const int NBK = (N + BK_NETS - 1) >> BK_SHIFT;
    const int NB = (P + CHUNK - 1) / CHUNK;

    // ws: recs[NBK][CAP] (8 B) | gcur[NBK]
    size_t recs_bytes = (size_t)NBK * CAP * sizeof(uint2);
    size_t need = recs_bytes + (size_t)NBK * sizeof(unsigned) + 256;

    hipMemsetAsync(d_out, 0, sizeof(float), stream);

    // Guard: mean bucket load + 8 sigma + 512 must fit in CAP.
    size_t mean_load = (NBK > 0) ? (size_t)P / (size_t)NBK : 0;
    size_t slack = 8 * (size_t)(__builtin_sqrt((double)(mean_load + 1))) + 512;
    bool cap_ok = (NBK > 0) && (mean_load + slack <= CAP);

    if (NBK > 0 && NBK <= NBK_MAX && (P & 3) == 0 && ws_size >= need && cap_ok) {
        uint2* recs = (uint2*)d_ws;
        unsigned* gcur = (unsigned*)((char*)d_ws + recs_bytes);
        hipMemsetAsync(gcur, 0, (size_t)NBK * sizeof(unsigned), stream);

        scatter_kernel<<<NB, TPB, 0, stream>>>(pos, p2n, gcur, recs, P, NBK);
        reduce_kernel<<<NBK, RTPB, 0, stream>>>(recs, gcur, mask, (float*)d_out, N);
    } else {
        unsigned* nets = (unsigned*)d_ws;
        hipMemsetAsync(d_ws, 0, (size_t)N * 4 * sizeof(unsigned), stream);
        fb_pin_kernel<<<(P + 255) / 256, 256, 0, stream>>>(pos, p2n, nets, P);
        fb_net_kernel<<<(N + 255) / 256, 256, 0, stream>>>((const uint4*)nets, mask,
                                                           (float*)d_out, N);
    }
}